// Round 4
// baseline (209.818 us; speedup 1.0000x reference)
//
#include <hip/hip_runtime.h>
#include <hip/hip_bf16.h>
#include <hip/hip_fp16.h>

#define B_  64
#define C_  32
#define N_  1152
#define DI_ 8
#define DC_ 16
#define STH 512              // 8 waves

// main-path geometry
#define HCH 2                // n's per staged chunk (wlds 32KB)
#define HSLOT 192            // chunk-slots; slot handles chunks slot, +192, +384

// fallback geometry (R5 path)
#define FCH 3
#define FSLOT 128

// ---------------- caps_pass: recompute hat in-registers, route in-flight ---
// R11 structural rewrite. The materialized-fp16-hat pipeline moved 310 MB
// (hat 75.5 MB written once + read twice dominated; route ran at ~2.2 TB/s
// on dirty/remote lines) -> ~49 us BW floor, ~110 us measured. The einsum is
// only 604 MFLOP = 3.8 us at fp32 vector peak, and W (19 MB) is L3-resident
// across passes -> recomputing hat every pass is ~3x cheaper in traffic.
// Per pass: read W (+accb), compute hat in regs, apply softmax weight
// (t=0: uniform 1/32), emit per-slot partial s into p1. accb accumulates
// squashed outputs across passes, so logit = dot(hat, accb) = summed
// agreement -- same semantics as before, now fp32 end-to-end.
__global__ __launch_bounds__(STH, 4) void caps_pass(
    const float* __restrict__ X, const float* __restrict__ W,
    const float* __restrict__ accb, float* __restrict__ p1, int t)
{
    __shared__ float wlds[HCH * 64 * 64];    // [nl][f=2c+h][phys quad q^(c&7)]

    const int xcd  = blockIdx.x & 7;
    const int k    = blockIdx.x >> 3;        // 0..95
    const int bg   = k & 3;                  // 0..3 (16 b's each)
    const int slot = 24 * xcd + (k >> 2);    // 0..191, contiguous band per XCD

    const int tid  = threadIdx.x;
    const int lane = tid & 63;
    const int c    = lane & 31;
    const int h    = lane >> 5;
    const int le   = 2 * c + h;
    const int sw   = c & 7;
    const int wu   = __builtin_amdgcn_readfirstlane(tid) >> 6;  // uniform wave id
    const int bl0  = wu * 2;

    float areg[2][8];
    if (t > 0) {
#pragma unroll
        for (int bq = 0; bq < 2; bq++) {
            const float* ap = accb + (size_t)(bg * 16 + bl0 + bq) * 512 + le * 8;
            const float4 a0 = *(const float4*)ap;
            const float4 a1 = *(const float4*)(ap + 4);
            areg[bq][0]=a0.x; areg[bq][1]=a0.y; areg[bq][2]=a0.z; areg[bq][3]=a0.w;
            areg[bq][4]=a1.x; areg[bq][5]=a1.y; areg[bq][6]=a1.z; areg[bq][7]=a1.w;
        }
    }

    float acc[2][8];
#pragma unroll
    for (int bq = 0; bq < 2; bq++)
#pragma unroll
        for (int r = 0; r < 8; r++) acc[bq][r] = 0.f;

    for (int cc = 0; cc < 3; cc++) {
        if (cc) __syncthreads();
        const int n0 = (slot + cc * HSLOT) * HCH;

#pragma unroll
        for (int G = tid; G < HCH * 1024; G += STH) {   // 4 iters
            const int nl = G >> 10, f = (G >> 4) & 63, q = G & 15;
            const int wc = f >> 1, wh = f & 1;
            const float4 v = *(const float4*)(W + (size_t)(wc * N_ + n0 + nl) * 128 + wh * 64 + q * 4);
            *(float4*)(wlds + (nl * 64 + f) * 64 + (q ^ (wc & 7)) * 4) = v;
        }
        __syncthreads();

#pragma unroll
        for (int nl = 0; nl < HCH; nl++) {
            float4 xa[2], xb[2];
#pragma unroll
            for (int bq = 0; bq < 2; bq++) {
                const float* xp = X + ((size_t)(bg * 16 + bl0 + bq) * N_ + n0 + nl) * DI_;
                xa[bq] = *(const float4*)xp;
                xb[bq] = *(const float4*)(xp + 4);
            }
            float hat[2][8];
            const float* frag = wlds + (nl * 64 + le) * 64;
#pragma unroll
            for (int rp = 0; rp < 4; rp++) {
                const int r0 = 2 * rp, r1 = r0 + 1;
                const int pa0 = ((2 * r0) ^ sw) * 4;
                const int pb0 = pa0 ^ 4;
                const int pa1 = ((2 * r1) ^ sw) * 4;
                const int pb1 = pa1 ^ 4;
                const float4 wa0 = *(const float4*)(frag + pa0);
                const float4 wb0 = *(const float4*)(frag + pb0);
                const float4 wa1 = *(const float4*)(frag + pa1);
                const float4 wb1 = *(const float4*)(frag + pb1);
#pragma unroll
                for (int bq = 0; bq < 2; bq++) {
                    hat[bq][r0] = wa0.x*xa[bq].x + wa0.y*xa[bq].y + wa0.z*xa[bq].z + wa0.w*xa[bq].w
                                + wb0.x*xb[bq].x + wb0.y*xb[bq].y + wb0.z*xb[bq].z + wb0.w*xb[bq].w;
                    hat[bq][r1] = wa1.x*xa[bq].x + wa1.y*xa[bq].y + wa1.z*xa[bq].z + wa1.w*xa[bq].w
                                + wb1.x*xb[bq].x + wb1.y*xb[bq].y + wb1.z*xb[bq].z + wb1.w*xb[bq].w;
                }
            }
            if (t == 0) {
#pragma unroll
                for (int bq = 0; bq < 2; bq++)
#pragma unroll
                    for (int r = 0; r < 8; r++) acc[bq][r] += 0.03125f * hat[bq][r];
            } else {
                // two softmax chains batched (2-way ILP on shuffle latency)
                float lg0 = hat[0][0]*areg[0][0] + hat[0][1]*areg[0][1]
                          + hat[0][2]*areg[0][2] + hat[0][3]*areg[0][3]
                          + hat[0][4]*areg[0][4] + hat[0][5]*areg[0][5]
                          + hat[0][6]*areg[0][6] + hat[0][7]*areg[0][7];
                float lg1 = hat[1][0]*areg[1][0] + hat[1][1]*areg[1][1]
                          + hat[1][2]*areg[1][2] + hat[1][3]*areg[1][3]
                          + hat[1][4]*areg[1][4] + hat[1][5]*areg[1][5]
                          + hat[1][6]*areg[1][6] + hat[1][7]*areg[1][7];
                lg0 += __shfl_xor(lg0, 32, 64);      // combine i-halves (same c)
                lg1 += __shfl_xor(lg1, 32, 64);
                const float e0 = __expf(lg0);        // no max-subtract: |lg| small
                const float e1 = __expf(lg1);
                float s0 = e0, s1 = e1;
#pragma unroll
                for (int m = 16; m >= 1; m >>= 1) {
                    s0 += __shfl_xor(s0, m, 64);
                    s1 += __shfl_xor(s1, m, 64);
                }
                const float sc0 = e0 * __builtin_amdgcn_rcpf(s0);
                const float sc1 = e1 * __builtin_amdgcn_rcpf(s1);
#pragma unroll
                for (int r = 0; r < 8; r++) {
                    acc[0][r] += sc0 * hat[0][r];
                    acc[1][r] += sc1 * hat[1][r];
                }
            }
        }
    }

    float* pout = p1 + (size_t)(bg * HSLOT + slot) * (16 * 512);
#pragma unroll
    for (int bq = 0; bq < 2; bq++) {
        float* pb = pout + (bl0 + bq) * 512 + le * 8;
        *(float4*)pb       = make_float4(acc[bq][0], acc[bq][1], acc[bq][2], acc[bq][3]);
        *(float4*)(pb + 4) = make_float4(acc[bq][4], acc[bq][5], acc[bq][6], acc[bq][7]);
    }
}

// ---------------- caps_r1: reduce 192 slot-slabs per bg, squash, update ----
// p1 layout [bg(4)*HSLOT + slot][16 b][512]
__global__ __launch_bounds__(512) void caps_r1(
    const float* __restrict__ p1, float* __restrict__ accb,
    float* __restrict__ out, int t)
{
    const int b   = blockIdx.x >> 2;
    const int q   = blockIdx.x & 3;
    const int tid = threadIdx.x;
    const int e   = q * 128 + (tid >> 2);
    const int p   = tid & 3;
    const int bg  = b >> 4, bl = b & 15;
    const float* base = p1 + (size_t)bg * HSLOT * 8192 + (size_t)bl * 512 + e;
    float v = 0.f;
#pragma unroll 8
    for (int ch = p; ch < HSLOT; ch += 4)
        v += base[(size_t)ch * 8192];
    v += __shfl_xor(v, 1, 64);
    v += __shfl_xor(v, 2, 64);
    float sq = v * v;
#pragma unroll
    for (int m = 4; m <= 32; m <<= 1) sq += __shfl_xor(sq, m, 64);
    const float scale = sq / (1.f + sq) * rsqrtf(sq + 1e-7f);
    const float ov = v * scale;
    if (p == 0) {
        const int oidx = b * 512 + e;
        if (t == 2) out[oidx] = ov;
        else        accb[oidx] = (t == 0) ? ov : (accb[oidx] + ov);
    }
}

// ---------------- fallback (R5 path, 16.9 MB ws) ---------------------------
__global__ __launch_bounds__(STH, 2) void caps_s_fb(
    const float* __restrict__ X, const float* __restrict__ W,
    const float* __restrict__ aout, float* __restrict__ partials, int t)
{
    __shared__ float wlds[FCH * 64 * 64];
    __shared__ float xlds[FCH * 16 * 8];
    const int bg = blockIdx.x & 3, slot = blockIdx.x >> 2;
    const int tid = threadIdx.x, w = tid >> 6, lane = tid & 63;
    const int c = lane & 31, h = lane >> 5, bl0 = w * 2, sw = c & 7;
    float areg[2][8] = {};
    if (t > 0) {
#pragma unroll
        for (int bq = 0; bq < 2; bq++) {
            const float* ap = aout + (size_t)(bg * 16 + bl0 + bq) * 512 + c * 16 + h * 8;
            const float4 a0 = *(const float4*)ap; const float4 a1 = *(const float4*)(ap + 4);
            areg[bq][0]=a0.x; areg[bq][1]=a0.y; areg[bq][2]=a0.z; areg[bq][3]=a0.w;
            areg[bq][4]=a1.x; areg[bq][5]=a1.y; areg[bq][6]=a1.z; areg[bq][7]=a1.w;
        }
    }
    float acc[2][8];
#pragma unroll
    for (int bq = 0; bq < 2; bq++)
#pragma unroll
        for (int r = 0; r < 8; r++) acc[bq][r] = 0.f;
    for (int cc = 0; cc < 3; cc++) {
        if (cc) __syncthreads();
        const int n0 = (slot + cc * FSLOT) * FCH;
        for (int G = tid; G < FCH * 1024; G += STH) {
            const int nl = G >> 10, f = (G >> 4) & 63, q = G & 15;
            const int wc = f >> 1, wh = f & 1;
            const float4 v = *(const float4*)(W + (size_t)(wc * N_ + n0 + nl) * 128 + wh * 64 + q * 4);
            *(float4*)(wlds + (nl * 64 + f) * 64 + (q ^ (wc & 7)) * 4) = v;
        }
        if (tid < FCH * 32) {
            const int nl = tid >> 5, bl = (tid >> 1) & 15, qx = tid & 1;
            const float4 v = *(const float4*)(X + (size_t)((bg * 16 + bl) * N_ + n0 + nl) * DI_ + qx * 4);
            *(float4*)(xlds + (nl * 16 + bl) * 8 + qx * 4) = v;
        }
        __syncthreads();
#pragma unroll
        for (int nl = 0; nl < FCH; nl++) {
            float4 xa[2], xb[2];
#pragma unroll
            for (int bq = 0; bq < 2; bq++) {
                const float* xp = xlds + (nl * 16 + bl0 + bq) * 8;
                xa[bq] = *(const float4*)xp; xb[bq] = *(const float4*)(xp + 4);
            }
            float hat[2][8];
            const float* frag = wlds + (nl * 64 + 2 * c + h) * 64;
#pragma unroll
            for (int r = 0; r < 8; r++) {
                const int pa = ((2 * r) ^ sw) * 4; const int pb = pa ^ 4;
                const float4 wa = *(const float4*)(frag + pa);
                const float4 wb = *(const float4*)(frag + pb);
#pragma unroll
                for (int bq = 0; bq < 2; bq++)
                    hat[bq][r] = wa.x*xa[bq].x + wa.y*xa[bq].y + wa.z*xa[bq].z + wa.w*xa[bq].w
                               + wb.x*xb[bq].x + wb.y*xb[bq].y + wb.z*xb[bq].z + wb.w*xb[bq].w;
            }
#pragma unroll
            for (int bq = 0; bq < 2; bq++) {
                float softc;
                if (t > 0) {
                    float lg = hat[bq][0]*areg[bq][0] + hat[bq][1]*areg[bq][1]
                             + hat[bq][2]*areg[bq][2] + hat[bq][3]*areg[bq][3]
                             + hat[bq][4]*areg[bq][4] + hat[bq][5]*areg[bq][5]
                             + hat[bq][6]*areg[bq][6] + hat[bq][7]*areg[bq][7];
                    lg += __shfl_xor(lg, 32, 64);
                    const float e = __expf(lg);
                    float s = e;
#pragma unroll
                    for (int m = 16; m >= 1; m >>= 1) s += __shfl_xor(s, m, 64);
                    softc = e / s;
                } else softc = 1.0f / 32.0f;
#pragma unroll
                for (int r = 0; r < 8; r++) acc[bq][r] += softc * hat[bq][r];
            }
        }
    }
    float* pout = partials + (size_t)(bg * FSLOT + slot) * (16 * 512);
#pragma unroll
    for (int bq = 0; bq < 2; bq++) {
        float* pb = pout + (bl0 + bq) * 512 + c * 16 + h * 8;
        *(float4*)pb       = make_float4(acc[bq][0], acc[bq][1], acc[bq][2], acc[bq][3]);
        *(float4*)(pb + 4) = make_float4(acc[bq][4], acc[bq][5], acc[bq][6], acc[bq][7]);
    }
}

__global__ __launch_bounds__(256) void caps_r1_fb(
    const float* __restrict__ partials, float* __restrict__ accb,
    float* __restrict__ out, int t)
{
    const int b   = blockIdx.x >> 2;
    const int q   = blockIdx.x & 3;
    const int tid = threadIdx.x;
    const int e   = q * 128 + (tid >> 1);
    const int p   = tid & 1;
    const int bg  = b >> 4, bl = b & 15;
    const float* base = partials + (size_t)bg * FSLOT * 8192 + (size_t)bl * 512 + e;
    float v = 0.f;
#pragma unroll 8
    for (int ch = p; ch < FSLOT; ch += 2)
        v += base[(size_t)ch * 8192];
    v += __shfl_xor(v, 1, 64);
    float sq = v * v;
#pragma unroll
    for (int m = 2; m <= 16; m <<= 1) sq += __shfl_xor(sq, m, 64);
    const float scale = sq / (1.f + sq) * rsqrtf(sq + 1e-7f);
    const float ov = v * scale;
    if (p == 0) {
        const int oidx = b * 512 + e;
        if (t == 2) out[oidx] = ov;
        else        accb[oidx] = (t == 0) ? ov : (accb[oidx] + ov);
    }
}

extern "C" void kernel_launch(void* const* d_in, const int* in_sizes, int n_in,
                              void* d_out, int out_size, void* d_ws, size_t ws_size,
                              hipStream_t stream) {
    const float* X = (const float*)d_in[0];   // [B,N,DI]
    const float* W = (const float*)d_in[1];   // [C,N,DC,DI]
    float* out = (float*)d_out;               // [B,C,DC]

    const size_t p1_b  = (size_t)4 * HSLOT * 8192 * 4;     // 25,165,824
    const size_t acc_b = (size_t)B_ * 512 * 4;             //    131,072

    if (ws_size >= p1_b + acc_b) {
        char* ws = (char*)d_ws;
        float* p1   = (float*)ws;
        float* accb = (float*)(ws + p1_b);
        for (int t = 0; t < 3; t++) {
            caps_pass<<<768, STH, 0, stream>>>(X, W, accb, p1, t);
            caps_r1  <<<256, 512, 0, stream>>>(p1, accb, out, t);
        }
    } else {
        float* partials = (float*)d_ws;
        float* accb = partials + (size_t)512 * 8192;
        for (int t = 0; t < 3; t++) {
            caps_s_fb<<<512, STH, 0, stream>>>(X, W, accb, partials, t);
            caps_r1_fb<<<256, 256, 0, stream>>>(partials, accb, out, t);
        }
    }
}

// Round 5
// 205.106 us; speedup vs baseline: 1.0230x; 1.0230x over previous
//
#include <hip/hip_runtime.h>
#include <hip/hip_bf16.h>
#include <hip/hip_fp16.h>

#define B_  64
#define C_  32
#define N_  1152
#define DI_ 8
#define DC_ 16
#define STH 512              // 8 waves

// main-path geometry
#define HCH 2                // n's per staged chunk (wlds 32KB)
#define HSLOT 192            // chunk-slots; slot handles chunks slot, +192, +384

// fallback geometry (R5 path)
#define FCH 3
#define FSLOT 128

static __device__ __forceinline__ unsigned pkh(float a, float b) {
    __half2 t = __float22half2_rn(make_float2(a, b));
    return *reinterpret_cast<unsigned*>(&t);
}

// ---------------- caps_pass: recompute hat in-registers, route in-flight ---
// R12: R11's pass was VALU-STALL bound (VALU 27%, HBM 27%, occ 30%; FMA floor
// is 3.8us vs 48us measured). Fixes:
//  (a) T14 reg-staged W prefetch: load chunk cc+1 into 4xfloat4 regs BEFORE
//      computing cc; ds_write after the barrier -> W latency hides under
//      compute. LDS stays single-buffer 32KB (swizzled layout kept).
//  (b) 4-way softmax-chain ILP: both nl's hats computed first (hat[2][2][8]),
//      then 4 chains (2b x 2nl) run every stage together -> shuffle/exp
//      latency amortized 4x (R11 had only 2-way).
//  (c) p1 emitted as fp16 (__half2): halves epilogue + r1 traffic.
__global__ __launch_bounds__(STH, 4) void caps_pass(
    const float* __restrict__ X, const float* __restrict__ W,
    const float* __restrict__ accb, __half2* __restrict__ p1, int t)
{
    __shared__ float wlds[HCH * 64 * 64];    // [nl][f=2c+h][phys quad q^(c&7)]

    const int xcd  = blockIdx.x & 7;
    const int k    = blockIdx.x >> 3;        // 0..95
    const int bg   = k & 3;                  // 0..3 (16 b's each)
    const int slot = 24 * xcd + (k >> 2);    // 0..191, contiguous band per XCD

    const int tid  = threadIdx.x;
    const int lane = tid & 63;
    const int c    = lane & 31;
    const int h    = lane >> 5;
    const int le   = 2 * c + h;
    const int sw   = c & 7;
    const int wu   = __builtin_amdgcn_readfirstlane(tid) >> 6;  // uniform wave id
    const int bl0  = wu * 2;

    // staging decode for this thread's 4 slices (G = tid + i*512)
    const int g_nl[4] = { (tid) >> 10, (tid + 512) >> 10, (tid + 1024) >> 10, (tid + 1536) >> 10 };
    const int g_f [4] = { (tid >> 4) & 63, ((tid + 512) >> 4) & 63, ((tid + 1024) >> 4) & 63, ((tid + 1536) >> 4) & 63 };
    const int g_q  = tid & 15;

    float areg[2][8];
    if (t > 0) {
#pragma unroll
        for (int bq = 0; bq < 2; bq++) {
            const float* ap = accb + (size_t)(bg * 16 + bl0 + bq) * 512 + le * 8;
            const float4 a0 = *(const float4*)ap;
            const float4 a1 = *(const float4*)(ap + 4);
            areg[bq][0]=a0.x; areg[bq][1]=a0.y; areg[bq][2]=a0.z; areg[bq][3]=a0.w;
            areg[bq][4]=a1.x; areg[bq][5]=a1.y; areg[bq][6]=a1.z; areg[bq][7]=a1.w;
        }
    }

    float acc[2][8];
#pragma unroll
    for (int bq = 0; bq < 2; bq++)
#pragma unroll
        for (int r = 0; r < 8; r++) acc[bq][r] = 0.f;

    float4 wreg[4];
    // prologue: stage chunk 0
    {
        const int n0 = slot * HCH;
#pragma unroll
        for (int i = 0; i < 4; i++) {
            const int wc = g_f[i] >> 1, wh = g_f[i] & 1;
            wreg[i] = *(const float4*)(W + (size_t)(wc * N_ + n0 + g_nl[i]) * 128 + wh * 64 + g_q * 4);
        }
#pragma unroll
        for (int i = 0; i < 4; i++) {
            const int wc = g_f[i] >> 1;
            *(float4*)(wlds + (g_nl[i] * 64 + g_f[i]) * 64 + (g_q ^ (wc & 7)) * 4) = wreg[i];
        }
    }
    __syncthreads();

    for (int cc = 0; cc < 3; cc++) {
        // T14: issue next chunk's global loads before compute (latency hides)
        if (cc < 2) {
            const int n0 = (slot + (cc + 1) * HSLOT) * HCH;
#pragma unroll
            for (int i = 0; i < 4; i++) {
                const int wc = g_f[i] >> 1, wh = g_f[i] & 1;
                wreg[i] = *(const float4*)(W + (size_t)(wc * N_ + n0 + g_nl[i]) * 128 + wh * 64 + g_q * 4);
            }
        }
        const int n0 = (slot + cc * HSLOT) * HCH;

        // compute hats for BOTH nl (32 regs) so softmax chains batch 4-wide
        float hat[2][2][8];
#pragma unroll
        for (int nl = 0; nl < HCH; nl++) {
            float4 xa[2], xb[2];
#pragma unroll
            for (int bq = 0; bq < 2; bq++) {
                const float* xp = X + ((size_t)(bg * 16 + bl0 + bq) * N_ + n0 + nl) * DI_;
                xa[bq] = *(const float4*)xp;
                xb[bq] = *(const float4*)(xp + 4);
            }
            const float* frag = wlds + (nl * 64 + le) * 64;
#pragma unroll
            for (int rp = 0; rp < 4; rp++) {
                const int r0 = 2 * rp, r1 = r0 + 1;
                const int pa0 = ((2 * r0) ^ sw) * 4;
                const int pb0 = pa0 ^ 4;
                const int pa1 = ((2 * r1) ^ sw) * 4;
                const int pb1 = pa1 ^ 4;
                const float4 wa0 = *(const float4*)(frag + pa0);
                const float4 wb0 = *(const float4*)(frag + pb0);
                const float4 wa1 = *(const float4*)(frag + pa1);
                const float4 wb1 = *(const float4*)(frag + pb1);
#pragma unroll
                for (int bq = 0; bq < 2; bq++) {
                    hat[nl][bq][r0] = wa0.x*xa[bq].x + wa0.y*xa[bq].y + wa0.z*xa[bq].z + wa0.w*xa[bq].w
                                    + wb0.x*xb[bq].x + wb0.y*xb[bq].y + wb0.z*xb[bq].z + wb0.w*xb[bq].w;
                    hat[nl][bq][r1] = wa1.x*xa[bq].x + wa1.y*xa[bq].y + wa1.z*xa[bq].z + wa1.w*xa[bq].w
                                    + wb1.x*xb[bq].x + wb1.y*xb[bq].y + wb1.z*xb[bq].z + wb1.w*xb[bq].w;
                }
            }
        }

        if (t == 0) {
#pragma unroll
            for (int nl = 0; nl < HCH; nl++)
#pragma unroll
                for (int bq = 0; bq < 2; bq++)
#pragma unroll
                    for (int r = 0; r < 8; r++)
                        acc[bq][r] += 0.03125f * hat[nl][bq][r];
        } else {
            // four softmax chains batched (4-way ILP on shuffle/exp latency)
            float lg[4], sm[4];
#pragma unroll
            for (int nl = 0; nl < HCH; nl++)
#pragma unroll
                for (int bq = 0; bq < 2; bq++) {
                    float s = 0.f;
#pragma unroll
                    for (int r = 0; r < 8; r++) s += hat[nl][bq][r] * areg[bq][r];
                    lg[nl * 2 + bq] = s;
                }
#pragma unroll
            for (int m = 0; m < 4; m++) lg[m] += __shfl_xor(lg[m], 32, 64);  // i-halves
#pragma unroll
            for (int m = 0; m < 4; m++) { lg[m] = __expf(lg[m]); sm[m] = lg[m]; }
#pragma unroll
            for (int d = 16; d >= 1; d >>= 1)
#pragma unroll
                for (int m = 0; m < 4; m++) sm[m] += __shfl_xor(sm[m], d, 64); // sum over c
#pragma unroll
            for (int nl = 0; nl < HCH; nl++)
#pragma unroll
                for (int bq = 0; bq < 2; bq++) {
                    const float sc = lg[nl * 2 + bq] * __builtin_amdgcn_rcpf(sm[nl * 2 + bq]);
#pragma unroll
                    for (int r = 0; r < 8; r++) acc[bq][r] += sc * hat[nl][bq][r];
                }
        }

        __syncthreads();                 // all waves done reading wlds
        if (cc < 2) {
#pragma unroll
            for (int i = 0; i < 4; i++) {   // vmcnt wait auto-inserted here
                const int wc = g_f[i] >> 1;
                *(float4*)(wlds + (g_nl[i] * 64 + g_f[i]) * 64 + (g_q ^ (wc & 7)) * 4) = wreg[i];
            }
            __syncthreads();             // wlds ready for next chunk
        }
    }

    // epilogue: fp16 partials, [slab][b 16][256 half2]
    __half2* pout = p1 + (size_t)(bg * HSLOT + slot) * (16 * 256);
#pragma unroll
    for (int bq = 0; bq < 2; bq++) {
        uint4 st;
        st.x = pkh(acc[bq][0], acc[bq][1]);
        st.y = pkh(acc[bq][2], acc[bq][3]);
        st.z = pkh(acc[bq][4], acc[bq][5]);
        st.w = pkh(acc[bq][6], acc[bq][7]);
        *(uint4*)(pout + (bl0 + bq) * 256 + le * 4) = st;
    }
}

// ---------------- caps_r1: reduce 192 fp16 slot-slabs, squash, update ------
// p1 layout [bg(4)*HSLOT + slot][16 b][256 half2]. Thread owns an e-PAIR
// (half2); 8-way chunk split over slabs; in-wave combine (p bits 0..2) then
// i-reduce (ep bits 0..2 = tid bits 3..5).
__global__ __launch_bounds__(512) void caps_r1(
    const __half2* __restrict__ p1, float* __restrict__ accb,
    float* __restrict__ out, int t)
{
    const int b   = blockIdx.x >> 2;     // 0..63
    const int q   = blockIdx.x & 3;
    const int tid = threadIdx.x;
    const int ep  = tid >> 3;            // 0..63: e-pair within q-range
    const int p   = tid & 7;             // 8-way slab split
    const int bg  = b >> 4, bl = b & 15;
    const __half2* base = p1 + (size_t)bg * HSLOT * 4096 + bl * 256 + (q * 64 + ep);
    float vx = 0.f, vy = 0.f;
#pragma unroll 8
    for (int ch = p; ch < HSLOT; ch += 8) {
        const float2 f = __half22float2(base[(size_t)ch * 4096]);
        vx += f.x; vy += f.y;
    }
    vx += __shfl_xor(vx, 1, 64);  vy += __shfl_xor(vy, 1, 64);
    vx += __shfl_xor(vx, 2, 64);  vy += __shfl_xor(vy, 2, 64);
    vx += __shfl_xor(vx, 4, 64);  vy += __shfl_xor(vy, 4, 64);
    float sq = vx * vx + vy * vy;
    sq += __shfl_xor(sq, 8, 64);
    sq += __shfl_xor(sq, 16, 64);
    sq += __shfl_xor(sq, 32, 64);
    const float scale = sq / (1.f + sq) * rsqrtf(sq + 1e-7f);
    if (p == 0) {
        const int oidx = b * 512 + q * 128 + ep * 2;
        const float ox = vx * scale, oy = vy * scale;
        if (t == 2) { out[oidx] = ox; out[oidx + 1] = oy; }
        else if (t == 0) { accb[oidx] = ox; accb[oidx + 1] = oy; }
        else { accb[oidx] += ox; accb[oidx + 1] += oy; }
    }
}

// ---------------- fallback (R5 path, 16.9 MB ws) ---------------------------
__global__ __launch_bounds__(STH, 2) void caps_s_fb(
    const float* __restrict__ X, const float* __restrict__ W,
    const float* __restrict__ aout, float* __restrict__ partials, int t)
{
    __shared__ float wlds[FCH * 64 * 64];
    __shared__ float xlds[FCH * 16 * 8];
    const int bg = blockIdx.x & 3, slot = blockIdx.x >> 2;
    const int tid = threadIdx.x, w = tid >> 6, lane = tid & 63;
    const int c = lane & 31, h = lane >> 5, bl0 = w * 2, sw = c & 7;
    float areg[2][8] = {};
    if (t > 0) {
#pragma unroll
        for (int bq = 0; bq < 2; bq++) {
            const float* ap = aout + (size_t)(bg * 16 + bl0 + bq) * 512 + c * 16 + h * 8;
            const float4 a0 = *(const float4*)ap; const float4 a1 = *(const float4*)(ap + 4);
            areg[bq][0]=a0.x; areg[bq][1]=a0.y; areg[bq][2]=a0.z; areg[bq][3]=a0.w;
            areg[bq][4]=a1.x; areg[bq][5]=a1.y; areg[bq][6]=a1.z; areg[bq][7]=a1.w;
        }
    }
    float acc[2][8];
#pragma unroll
    for (int bq = 0; bq < 2; bq++)
#pragma unroll
        for (int r = 0; r < 8; r++) acc[bq][r] = 0.f;
    for (int cc = 0; cc < 3; cc++) {
        if (cc) __syncthreads();
        const int n0 = (slot + cc * FSLOT) * FCH;
        for (int G = tid; G < FCH * 1024; G += STH) {
            const int nl = G >> 10, f = (G >> 4) & 63, q = G & 15;
            const int wc = f >> 1, wh = f & 1;
            const float4 v = *(const float4*)(W + (size_t)(wc * N_ + n0 + nl) * 128 + wh * 64 + q * 4);
            *(float4*)(wlds + (nl * 64 + f) * 64 + (q ^ (wc & 7)) * 4) = v;
        }
        if (tid < FCH * 32) {
            const int nl = tid >> 5, bl = (tid >> 1) & 15, qx = tid & 1;
            const float4 v = *(const float4*)(X + (size_t)((bg * 16 + bl) * N_ + n0 + nl) * DI_ + qx * 4);
            *(float4*)(xlds + (nl * 16 + bl) * 8 + qx * 4) = v;
        }
        __syncthreads();
#pragma unroll
        for (int nl = 0; nl < FCH; nl++) {
            float4 xa[2], xb[2];
#pragma unroll
            for (int bq = 0; bq < 2; bq++) {
                const float* xp = xlds + (nl * 16 + bl0 + bq) * 8;
                xa[bq] = *(const float4*)xp; xb[bq] = *(const float4*)(xp + 4);
            }
            float hat[2][8];
            const float* frag = wlds + (nl * 64 + 2 * c + h) * 64;
#pragma unroll
            for (int r = 0; r < 8; r++) {
                const int pa = ((2 * r) ^ sw) * 4; const int pb = pa ^ 4;
                const float4 wa = *(const float4*)(frag + pa);
                const float4 wb = *(const float4*)(frag + pb);
#pragma unroll
                for (int bq = 0; bq < 2; bq++)
                    hat[bq][r] = wa.x*xa[bq].x + wa.y*xa[bq].y + wa.z*xa[bq].z + wa.w*xa[bq].w
                               + wb.x*xb[bq].x + wb.y*xb[bq].y + wb.z*xb[bq].z + wb.w*xb[bq].w;
            }
#pragma unroll
            for (int bq = 0; bq < 2; bq++) {
                float softc;
                if (t > 0) {
                    float lg = hat[bq][0]*areg[bq][0] + hat[bq][1]*areg[bq][1]
                             + hat[bq][2]*areg[bq][2] + hat[bq][3]*areg[bq][3]
                             + hat[bq][4]*areg[bq][4] + hat[bq][5]*areg[bq][5]
                             + hat[bq][6]*areg[bq][6] + hat[bq][7]*areg[bq][7];
                    lg += __shfl_xor(lg, 32, 64);
                    const float e = __expf(lg);
                    float s = e;
#pragma unroll
                    for (int m = 16; m >= 1; m >>= 1) s += __shfl_xor(s, m, 64);
                    softc = e / s;
                } else softc = 1.0f / 32.0f;
#pragma unroll
                for (int r = 0; r < 8; r++) acc[bq][r] += softc * hat[bq][r];
            }
        }
    }
    float* pout = partials + (size_t)(bg * FSLOT + slot) * (16 * 512);
#pragma unroll
    for (int bq = 0; bq < 2; bq++) {
        float* pb = pout + (bl0 + bq) * 512 + c * 16 + h * 8;
        *(float4*)pb       = make_float4(acc[bq][0], acc[bq][1], acc[bq][2], acc[bq][3]);
        *(float4*)(pb + 4) = make_float4(acc[bq][4], acc[bq][5], acc[bq][6], acc[bq][7]);
    }
}

__global__ __launch_bounds__(256) void caps_r1_fb(
    const float* __restrict__ partials, float* __restrict__ accb,
    float* __restrict__ out, int t)
{
    const int b   = blockIdx.x >> 2;
    const int q   = blockIdx.x & 3;
    const int tid = threadIdx.x;
    const int e   = q * 128 + (tid >> 1);
    const int p   = tid & 1;
    const int bg  = b >> 4, bl = b & 15;
    const float* base = partials + (size_t)bg * FSLOT * 8192 + (size_t)bl * 512 + e;
    float v = 0.f;
#pragma unroll 8
    for (int ch = p; ch < FSLOT; ch += 2)
        v += base[(size_t)ch * 8192];
    v += __shfl_xor(v, 1, 64);
    float sq = v * v;
#pragma unroll
    for (int m = 2; m <= 16; m <<= 1) sq += __shfl_xor(sq, m, 64);
    const float scale = sq / (1.f + sq) * rsqrtf(sq + 1e-7f);
    const float ov = v * scale;
    if (p == 0) {
        const int oidx = b * 512 + e;
        if (t == 2) out[oidx] = ov;
        else        accb[oidx] = (t == 0) ? ov : (accb[oidx] + ov);
    }
}

extern "C" void kernel_launch(void* const* d_in, const int* in_sizes, int n_in,
                              void* d_out, int out_size, void* d_ws, size_t ws_size,
                              hipStream_t stream) {
    const float* X = (const float*)d_in[0];   // [B,N,DI]
    const float* W = (const float*)d_in[1];   // [C,N,DC,DI]
    float* out = (float*)d_out;               // [B,C,DC]

    const size_t p1_b  = (size_t)4 * HSLOT * 4096 * 4;     // 12,582,912 (fp16)
    const size_t acc_b = (size_t)B_ * 512 * 4;             //    131,072

    if (ws_size >= p1_b + acc_b) {
        char* ws = (char*)d_ws;
        __half2* p1 = (__half2*)ws;
        float* accb = (float*)(ws + p1_b);
        for (int t = 0; t < 3; t++) {
            caps_pass<<<768, STH, 0, stream>>>(X, W, accb, p1, t);
            caps_r1  <<<256, 512, 0, stream>>>(p1, accb, out, t);
        }
    } else {
        float* partials = (float*)d_ws;
        float* accb = partials + (size_t)512 * 8192;
        for (int t = 0; t < 3; t++) {
            caps_s_fb<<<512, STH, 0, stream>>>(X, W, accb, partials, t);
            caps_r1_fb<<<256, 256, 0, stream>>>(partials, accb, out, t);
        }
    }
}

// Round 6
// 189.872 us; speedup vs baseline: 1.1051x; 1.0802x over previous
//
#include <hip/hip_runtime.h>
#include <hip/hip_bf16.h>
#include <hip/hip_fp16.h>

#define B_  64
#define C_  32
#define N_  1152
#define DI_ 8
#define DC_ 16
#define STH 512              // 8 waves

// main-path geometry
#define HCH 2                // n's per staged chunk (wlds 32KB)
#define HSLOT 192            // chunk-slots; slot handles chunks slot, +192, +384

// fallback geometry (R5 path)
#define FCH 3
#define FSLOT 128

static __device__ __forceinline__ unsigned pkh(float a, float b) {
    __half2 t = __float22half2_rn(make_float2(a, b));
    return *reinterpret_cast<unsigned*>(&t);
}

// ---------------- caps_pass: recompute hat in-registers, route in-flight ---
// R13 SPILL FIX. R11/R12 ran with VGPR_Count=64 + WRITE_SIZE 72-96MB (p1 is
// only 13-25MB) -> massive scratch spill traffic was the 48us. Cause:
// __launch_bounds__(512,4) makes the backend budget registers for 8 waves/EU
// (64 VGPR) and spill; (512,2) budgets 128 (R0 evidence: 112 VGPR, zero
// spill, WRITE == exactly the intended bytes). Revert to (512,2) and trim
// state to ~110 regs: per-nl hat (2-chain softmax ILP), keep T14 W-prefetch
// (wreg[4]) and fp16 p1.
__global__ __launch_bounds__(STH, 2) void caps_pass(
    const float* __restrict__ X, const float* __restrict__ W,
    const float* __restrict__ accb, __half2* __restrict__ p1, int t)
{
    __shared__ float wlds[HCH * 64 * 64];    // [nl][f=2c+h][phys quad q^(c&7)]

    const int xcd  = blockIdx.x & 7;
    const int k    = blockIdx.x >> 3;        // 0..95
    const int bg   = k & 3;                  // 0..3 (16 b's each)
    const int slot = 24 * xcd + (k >> 2);    // 0..191, contiguous band per XCD

    const int tid  = threadIdx.x;
    const int lane = tid & 63;
    const int c    = lane & 31;
    const int h    = lane >> 5;
    const int le   = 2 * c + h;
    const int sw   = c & 7;
    const int wu   = __builtin_amdgcn_readfirstlane(tid) >> 6;  // uniform wave id
    const int bl0  = wu * 2;

    // staging decode for this thread's 4 slices (G = tid + i*512)
    const int g_nl[4] = { (tid) >> 10, (tid + 512) >> 10, (tid + 1024) >> 10, (tid + 1536) >> 10 };
    const int g_f [4] = { (tid >> 4) & 63, ((tid + 512) >> 4) & 63, ((tid + 1024) >> 4) & 63, ((tid + 1536) >> 4) & 63 };
    const int g_q  = tid & 15;

    float areg[2][8];
    if (t > 0) {
#pragma unroll
        for (int bq = 0; bq < 2; bq++) {
            const float* ap = accb + (size_t)(bg * 16 + bl0 + bq) * 512 + le * 8;
            const float4 a0 = *(const float4*)ap;
            const float4 a1 = *(const float4*)(ap + 4);
            areg[bq][0]=a0.x; areg[bq][1]=a0.y; areg[bq][2]=a0.z; areg[bq][3]=a0.w;
            areg[bq][4]=a1.x; areg[bq][5]=a1.y; areg[bq][6]=a1.z; areg[bq][7]=a1.w;
        }
    }

    float acc[2][8];
#pragma unroll
    for (int bq = 0; bq < 2; bq++)
#pragma unroll
        for (int r = 0; r < 8; r++) acc[bq][r] = 0.f;

    float4 wreg[4];
    // prologue: stage chunk 0
    {
        const int n0 = slot * HCH;
#pragma unroll
        for (int i = 0; i < 4; i++) {
            const int wc = g_f[i] >> 1, wh = g_f[i] & 1;
            wreg[i] = *(const float4*)(W + (size_t)(wc * N_ + n0 + g_nl[i]) * 128 + wh * 64 + g_q * 4);
        }
#pragma unroll
        for (int i = 0; i < 4; i++) {
            const int wc = g_f[i] >> 1;
            *(float4*)(wlds + (g_nl[i] * 64 + g_f[i]) * 64 + (g_q ^ (wc & 7)) * 4) = wreg[i];
        }
    }
    __syncthreads();

    for (int cc = 0; cc < 3; cc++) {
        // T14: issue next chunk's global loads before compute (latency hides)
        if (cc < 2) {
            const int n0 = (slot + (cc + 1) * HSLOT) * HCH;
#pragma unroll
            for (int i = 0; i < 4; i++) {
                const int wc = g_f[i] >> 1, wh = g_f[i] & 1;
                wreg[i] = *(const float4*)(W + (size_t)(wc * N_ + n0 + g_nl[i]) * 128 + wh * 64 + g_q * 4);
            }
        }
        const int n0 = (slot + cc * HSLOT) * HCH;

#pragma unroll
        for (int nl = 0; nl < HCH; nl++) {
            float4 xa[2], xb[2];
#pragma unroll
            for (int bq = 0; bq < 2; bq++) {
                const float* xp = X + ((size_t)(bg * 16 + bl0 + bq) * N_ + n0 + nl) * DI_;
                xa[bq] = *(const float4*)xp;
                xb[bq] = *(const float4*)(xp + 4);
            }
            float hat[2][8];
            const float* frag = wlds + (nl * 64 + le) * 64;
#pragma unroll
            for (int rp = 0; rp < 4; rp++) {
                const int r0 = 2 * rp, r1 = r0 + 1;
                const int pa0 = ((2 * r0) ^ sw) * 4;
                const int pb0 = pa0 ^ 4;
                const int pa1 = ((2 * r1) ^ sw) * 4;
                const int pb1 = pa1 ^ 4;
                const float4 wa0 = *(const float4*)(frag + pa0);
                const float4 wb0 = *(const float4*)(frag + pb0);
                const float4 wa1 = *(const float4*)(frag + pa1);
                const float4 wb1 = *(const float4*)(frag + pb1);
#pragma unroll
                for (int bq = 0; bq < 2; bq++) {
                    hat[bq][r0] = wa0.x*xa[bq].x + wa0.y*xa[bq].y + wa0.z*xa[bq].z + wa0.w*xa[bq].w
                                + wb0.x*xb[bq].x + wb0.y*xb[bq].y + wb0.z*xb[bq].z + wb0.w*xb[bq].w;
                    hat[bq][r1] = wa1.x*xa[bq].x + wa1.y*xa[bq].y + wa1.z*xa[bq].z + wa1.w*xa[bq].w
                                + wb1.x*xb[bq].x + wb1.y*xb[bq].y + wb1.z*xb[bq].z + wb1.w*xb[bq].w;
                }
            }
            if (t == 0) {
#pragma unroll
                for (int bq = 0; bq < 2; bq++)
#pragma unroll
                    for (int r = 0; r < 8; r++) acc[bq][r] += 0.03125f * hat[bq][r];
            } else {
                // two softmax chains batched (2-way ILP on shuffle/exp latency)
                float lg0 = hat[0][0]*areg[0][0] + hat[0][1]*areg[0][1]
                          + hat[0][2]*areg[0][2] + hat[0][3]*areg[0][3]
                          + hat[0][4]*areg[0][4] + hat[0][5]*areg[0][5]
                          + hat[0][6]*areg[0][6] + hat[0][7]*areg[0][7];
                float lg1 = hat[1][0]*areg[1][0] + hat[1][1]*areg[1][1]
                          + hat[1][2]*areg[1][2] + hat[1][3]*areg[1][3]
                          + hat[1][4]*areg[1][4] + hat[1][5]*areg[1][5]
                          + hat[1][6]*areg[1][6] + hat[1][7]*areg[1][7];
                lg0 += __shfl_xor(lg0, 32, 64);      // combine i-halves (same c)
                lg1 += __shfl_xor(lg1, 32, 64);
                const float e0 = __expf(lg0);        // no max-subtract: |lg| small
                const float e1 = __expf(lg1);
                float s0 = e0, s1 = e1;
#pragma unroll
                for (int m = 16; m >= 1; m >>= 1) {
                    s0 += __shfl_xor(s0, m, 64);
                    s1 += __shfl_xor(s1, m, 64);
                }
                const float sc0 = e0 * __builtin_amdgcn_rcpf(s0);
                const float sc1 = e1 * __builtin_amdgcn_rcpf(s1);
#pragma unroll
                for (int r = 0; r < 8; r++) {
                    acc[0][r] += sc0 * hat[0][r];
                    acc[1][r] += sc1 * hat[1][r];
                }
            }
        }

        __syncthreads();                 // all waves done reading wlds
        if (cc < 2) {
#pragma unroll
            for (int i = 0; i < 4; i++) {   // vmcnt wait auto-inserted here
                const int wc = g_f[i] >> 1;
                *(float4*)(wlds + (g_nl[i] * 64 + g_f[i]) * 64 + (g_q ^ (wc & 7)) * 4) = wreg[i];
            }
            __syncthreads();             // wlds ready for next chunk
        }
    }

    // epilogue: fp16 partials, [slab][b 16][256 half2]
    __half2* pout = p1 + (size_t)(bg * HSLOT + slot) * (16 * 256);
#pragma unroll
    for (int bq = 0; bq < 2; bq++) {
        uint4 st;
        st.x = pkh(acc[bq][0], acc[bq][1]);
        st.y = pkh(acc[bq][2], acc[bq][3]);
        st.z = pkh(acc[bq][4], acc[bq][5]);
        st.w = pkh(acc[bq][6], acc[bq][7]);
        *(uint4*)(pout + (bl0 + bq) * 256 + le * 4) = st;
    }
}

// ---------------- caps_r1: reduce 192 fp16 slot-slabs, squash, update ------
// p1 layout [bg(4)*HSLOT + slot][16 b][256 half2]. Thread owns an e-PAIR
// (half2); 8-way chunk split over slabs; in-wave combine (p bits 0..2) then
// i-reduce (ep bits 0..2 = tid bits 3..5).
__global__ __launch_bounds__(512) void caps_r1(
    const __half2* __restrict__ p1, float* __restrict__ accb,
    float* __restrict__ out, int t)
{
    const int b   = blockIdx.x >> 2;     // 0..63
    const int q   = blockIdx.x & 3;
    const int tid = threadIdx.x;
    const int ep  = tid >> 3;            // 0..63: e-pair within q-range
    const int p   = tid & 7;             // 8-way slab split
    const int bg  = b >> 4, bl = b & 15;
    const __half2* base = p1 + (size_t)bg * HSLOT * 4096 + bl * 256 + (q * 64 + ep);
    float vx = 0.f, vy = 0.f;
#pragma unroll 8
    for (int ch = p; ch < HSLOT; ch += 8) {
        const float2 f = __half22float2(base[(size_t)ch * 4096]);
        vx += f.x; vy += f.y;
    }
    vx += __shfl_xor(vx, 1, 64);  vy += __shfl_xor(vy, 1, 64);
    vx += __shfl_xor(vx, 2, 64);  vy += __shfl_xor(vy, 2, 64);
    vx += __shfl_xor(vx, 4, 64);  vy += __shfl_xor(vy, 4, 64);
    float sq = vx * vx + vy * vy;
    sq += __shfl_xor(sq, 8, 64);
    sq += __shfl_xor(sq, 16, 64);
    sq += __shfl_xor(sq, 32, 64);
    const float scale = sq / (1.f + sq) * rsqrtf(sq + 1e-7f);
    if (p == 0) {
        const int oidx = b * 512 + q * 128 + ep * 2;
        const float ox = vx * scale, oy = vy * scale;
        if (t == 2) { out[oidx] = ox; out[oidx + 1] = oy; }
        else if (t == 0) { accb[oidx] = ox; accb[oidx + 1] = oy; }
        else { accb[oidx] += ox; accb[oidx + 1] += oy; }
    }
}

// ---------------- fallback (R5 path, 16.9 MB ws) ---------------------------
__global__ __launch_bounds__(STH, 2) void caps_s_fb(
    const float* __restrict__ X, const float* __restrict__ W,
    const float* __restrict__ aout, float* __restrict__ partials, int t)
{
    __shared__ float wlds[FCH * 64 * 64];
    __shared__ float xlds[FCH * 16 * 8];
    const int bg = blockIdx.x & 3, slot = blockIdx.x >> 2;
    const int tid = threadIdx.x, w = tid >> 6, lane = tid & 63;
    const int c = lane & 31, h = lane >> 5, bl0 = w * 2, sw = c & 7;
    float areg[2][8] = {};
    if (t > 0) {
#pragma unroll
        for (int bq = 0; bq < 2; bq++) {
            const float* ap = aout + (size_t)(bg * 16 + bl0 + bq) * 512 + c * 16 + h * 8;
            const float4 a0 = *(const float4*)ap; const float4 a1 = *(const float4*)(ap + 4);
            areg[bq][0]=a0.x; areg[bq][1]=a0.y; areg[bq][2]=a0.z; areg[bq][3]=a0.w;
            areg[bq][4]=a1.x; areg[bq][5]=a1.y; areg[bq][6]=a1.z; areg[bq][7]=a1.w;
        }
    }
    float acc[2][8];
#pragma unroll
    for (int bq = 0; bq < 2; bq++)
#pragma unroll
        for (int r = 0; r < 8; r++) acc[bq][r] = 0.f;
    for (int cc = 0; cc < 3; cc++) {
        if (cc) __syncthreads();
        const int n0 = (slot + cc * FSLOT) * FCH;
        for (int G = tid; G < FCH * 1024; G += STH) {
            const int nl = G >> 10, f = (G >> 4) & 63, q = G & 15;
            const int wc = f >> 1, wh = f & 1;
            const float4 v = *(const float4*)(W + (size_t)(wc * N_ + n0 + nl) * 128 + wh * 64 + q * 4);
            *(float4*)(wlds + (nl * 64 + f) * 64 + (q ^ (wc & 7)) * 4) = v;
        }
        if (tid < FCH * 32) {
            const int nl = tid >> 5, bl = (tid >> 1) & 15, qx = tid & 1;
            const float4 v = *(const float4*)(X + (size_t)((bg * 16 + bl) * N_ + n0 + nl) * DI_ + qx * 4);
            *(float4*)(xlds + (nl * 16 + bl) * 8 + qx * 4) = v;
        }
        __syncthreads();
#pragma unroll
        for (int nl = 0; nl < FCH; nl++) {
            float4 xa[2], xb[2];
#pragma unroll
            for (int bq = 0; bq < 2; bq++) {
                const float* xp = xlds + (nl * 16 + bl0 + bq) * 8;
                xa[bq] = *(const float4*)xp; xb[bq] = *(const float4*)(xp + 4);
            }
            float hat[2][8];
            const float* frag = wlds + (nl * 64 + 2 * c + h) * 64;
#pragma unroll
            for (int r = 0; r < 8; r++) {
                const int pa = ((2 * r) ^ sw) * 4; const int pb = pa ^ 4;
                const float4 wa = *(const float4*)(frag + pa);
                const float4 wb = *(const float4*)(frag + pb);
#pragma unroll
                for (int bq = 0; bq < 2; bq++)
                    hat[bq][r] = wa.x*xa[bq].x + wa.y*xa[bq].y + wa.z*xa[bq].z + wa.w*xa[bq].w
                               + wb.x*xb[bq].x + wb.y*xb[bq].y + wb.z*xb[bq].z + wb.w*xb[bq].w;
            }
#pragma unroll
            for (int bq = 0; bq < 2; bq++) {
                float softc;
                if (t > 0) {
                    float lg = hat[bq][0]*areg[bq][0] + hat[bq][1]*areg[bq][1]
                             + hat[bq][2]*areg[bq][2] + hat[bq][3]*areg[bq][3]
                             + hat[bq][4]*areg[bq][4] + hat[bq][5]*areg[bq][5]
                             + hat[bq][6]*areg[bq][6] + hat[bq][7]*areg[bq][7];
                    lg += __shfl_xor(lg, 32, 64);
                    const float e = __expf(lg);
                    float s = e;
#pragma unroll
                    for (int m = 16; m >= 1; m >>= 1) s += __shfl_xor(s, m, 64);
                    softc = e / s;
                } else softc = 1.0f / 32.0f;
#pragma unroll
                for (int r = 0; r < 8; r++) acc[bq][r] += softc * hat[bq][r];
            }
        }
    }
    float* pout = partials + (size_t)(bg * FSLOT + slot) * (16 * 512);
#pragma unroll
    for (int bq = 0; bq < 2; bq++) {
        float* pb = pout + (bl0 + bq) * 512 + c * 16 + h * 8;
        *(float4*)pb       = make_float4(acc[bq][0], acc[bq][1], acc[bq][2], acc[bq][3]);
        *(float4*)(pb + 4) = make_float4(acc[bq][4], acc[bq][5], acc[bq][6], acc[bq][7]);
    }
}

__global__ __launch_bounds__(256) void caps_r1_fb(
    const float* __restrict__ partials, float* __restrict__ accb,
    float* __restrict__ out, int t)
{
    const int b   = blockIdx.x >> 2;
    const int q   = blockIdx.x & 3;
    const int tid = threadIdx.x;
    const int e   = q * 128 + (tid >> 1);
    const int p   = tid & 1;
    const int bg  = b >> 4, bl = b & 15;
    const float* base = partials + (size_t)bg * FSLOT * 8192 + (size_t)bl * 512 + e;
    float v = 0.f;
#pragma unroll 8
    for (int ch = p; ch < FSLOT; ch += 2)
        v += base[(size_t)ch * 8192];
    v += __shfl_xor(v, 1, 64);
    float sq = v * v;
#pragma unroll
    for (int m = 2; m <= 16; m <<= 1) sq += __shfl_xor(sq, m, 64);
    const float scale = sq / (1.f + sq) * rsqrtf(sq + 1e-7f);
    const float ov = v * scale;
    if (p == 0) {
        const int oidx = b * 512 + e;
        if (t == 2) out[oidx] = ov;
        else        accb[oidx] = (t == 0) ? ov : (accb[oidx] + ov);
    }
}

extern "C" void kernel_launch(void* const* d_in, const int* in_sizes, int n_in,
                              void* d_out, int out_size, void* d_ws, size_t ws_size,
                              hipStream_t stream) {
    const float* X = (const float*)d_in[0];   // [B,N,DI]
    const float* W = (const float*)d_in[1];   // [C,N,DC,DI]
    float* out = (float*)d_out;               // [B,C,DC]

    const size_t p1_b  = (size_t)4 * HSLOT * 4096 * 4;     // 12,582,912 (fp16)
    const size_t acc_b = (size_t)B_ * 512 * 4;             //    131,072

    if (ws_size >= p1_b + acc_b) {
        char* ws = (char*)d_ws;
        __half2* p1 = (__half2*)ws;
        float* accb = (float*)(ws + p1_b);
        for (int t = 0; t < 3; t++) {
            caps_pass<<<768, STH, 0, stream>>>(X, W, accb, p1, t);
            caps_r1  <<<256, 512, 0, stream>>>(p1, accb, out, t);
        }
    } else {
        float* partials = (float*)d_ws;
        float* accb = partials + (size_t)512 * 8192;
        for (int t = 0; t < 3; t++) {
            caps_s_fb<<<512, STH, 0, stream>>>(X, W, accb, partials, t);
            caps_r1_fb<<<256, 256, 0, stream>>>(partials, accb, out, t);
        }
    }
}

// Round 8
// 144.100 us; speedup vs baseline: 1.4561x; 1.3176x over previous
//
#include <hip/hip_runtime.h>
#include <hip/hip_bf16.h>
#include <hip/hip_fp16.h>

#define B_  64
#define C_  32
#define N_  1152
#define DI_ 8
#define DC_ 16
#define STH 512              // 8 waves

// main-path geometry
#define HCH 2                // n's per staged chunk (wlds 32KB)
#define HSLOT 192            // chunk-slots; slot handles chunks slot, +192, +384
#define NOCT 24              // route units of 48 n = one XCD's slot band

// fallback geometry (R5 path)
#define FCH 3
#define FSLOT 128

static __device__ __forceinline__ unsigned pkh(float a, float b) {
    __half2 t = __float22half2_rn(make_float2(a, b));
    return *reinterpret_cast<unsigned*>(&t);
}
static __device__ __forceinline__ float2 uph(unsigned u) {
    __half2 h; *reinterpret_cast<unsigned*>(&h) = u;
    return __half22float2(h);
}

// ---------------- caps_hat: hat = W@x once, fp16 out, + t=0 partials -------
// R15: cooperative grid-sync is incompatible with the harness (R7 failure) ->
// back to materialized-hat, but SPILL-FREE for the first time. R2's 126us
// best ran caps_hat at (512,4) = the 64-VGPR spill regime (R5 discovery);
// (512,2) is the verified 112-VGPR no-spill regime (R0). Geometry from the
// verified R13 pass: HCH=2 (32KB LDS -> 2 blocks/CU), T14 reg-prefetch of W,
// XCD-banded slots (24/xcd, contiguous 48-n band per cc), direct X loads.
__global__ __launch_bounds__(STH, 2) void caps_hat(
    const float* __restrict__ X, const float* __restrict__ W,
    uint4* __restrict__ hatg, __half2* __restrict__ p1)
{
    __shared__ float wlds[HCH * 64 * 64];    // [nl][f=2c+h][phys quad q^(c&7)]

    const int xcd  = blockIdx.x & 7;
    const int k    = blockIdx.x >> 3;        // 0..95
    const int bg   = k & 3;                  // 0..3 (16 b's each)
    const int slot = 24 * xcd + (k >> 2);    // 0..191, contiguous band per XCD

    const int tid  = threadIdx.x;
    const int lane = tid & 63;
    const int c    = lane & 31;
    const int h    = lane >> 5;
    const int le   = 2 * c + h;
    const int sw   = c & 7;
    const int wu   = __builtin_amdgcn_readfirstlane(tid) >> 6;  // uniform wave id
    const int bl0  = wu * 2;

    // staging decode for this thread's 4 slices (G = tid + i*512)
    const int g_nl[4] = { (tid) >> 10, (tid + 512) >> 10, (tid + 1024) >> 10, (tid + 1536) >> 10 };
    const int g_f [4] = { (tid >> 4) & 63, ((tid + 512) >> 4) & 63, ((tid + 1024) >> 4) & 63, ((tid + 1536) >> 4) & 63 };
    const int g_q  = tid & 15;

    float acc[2][8];
#pragma unroll
    for (int bq = 0; bq < 2; bq++)
#pragma unroll
        for (int r = 0; r < 8; r++) acc[bq][r] = 0.f;

    float4 wreg[4];
    // prologue: stage chunk 0
    {
        const int n0 = slot * HCH;
#pragma unroll
        for (int i = 0; i < 4; i++) {
            const int wc = g_f[i] >> 1, wh = g_f[i] & 1;
            wreg[i] = *(const float4*)(W + (size_t)(wc * N_ + n0 + g_nl[i]) * 128 + wh * 64 + g_q * 4);
        }
#pragma unroll
        for (int i = 0; i < 4; i++) {
            const int wc = g_f[i] >> 1;
            *(float4*)(wlds + (g_nl[i] * 64 + g_f[i]) * 64 + (g_q ^ (wc & 7)) * 4) = wreg[i];
        }
    }
    __syncthreads();

    for (int cc = 0; cc < 3; cc++) {
        // T14: issue next chunk's global loads before compute (latency hides)
        if (cc < 2) {
            const int n0 = (slot + (cc + 1) * HSLOT) * HCH;
#pragma unroll
            for (int i = 0; i < 4; i++) {
                const int wc = g_f[i] >> 1, wh = g_f[i] & 1;
                wreg[i] = *(const float4*)(W + (size_t)(wc * N_ + n0 + g_nl[i]) * 128 + wh * 64 + g_q * 4);
            }
        }
        const int n0 = (slot + cc * HSLOT) * HCH;

#pragma unroll
        for (int nl = 0; nl < HCH; nl++) {
            float4 xa[2], xb[2];
#pragma unroll
            for (int bq = 0; bq < 2; bq++) {
                const float* xp = X + ((size_t)(bg * 16 + bl0 + bq) * N_ + n0 + nl) * DI_;
                xa[bq] = *(const float4*)xp;
                xb[bq] = *(const float4*)(xp + 4);
            }
            uint4 hq[2];
            const float* frag = wlds + (nl * 64 + le) * 64;
#pragma unroll
            for (int rp = 0; rp < 4; rp++) {
                const int r0 = 2 * rp, r1 = r0 + 1;
                const int pa0 = ((2 * r0) ^ sw) * 4;
                const int pb0 = pa0 ^ 4;
                const int pa1 = ((2 * r1) ^ sw) * 4;
                const int pb1 = pa1 ^ 4;
                const float4 wa0 = *(const float4*)(frag + pa0);
                const float4 wb0 = *(const float4*)(frag + pb0);
                const float4 wa1 = *(const float4*)(frag + pa1);
                const float4 wb1 = *(const float4*)(frag + pb1);
#pragma unroll
                for (int bq = 0; bq < 2; bq++) {
                    const float hv0 = wa0.x*xa[bq].x + wa0.y*xa[bq].y + wa0.z*xa[bq].z + wa0.w*xa[bq].w
                                    + wb0.x*xb[bq].x + wb0.y*xb[bq].y + wb0.z*xb[bq].z + wb0.w*xb[bq].w;
                    const float hv1 = wa1.x*xa[bq].x + wa1.y*xa[bq].y + wa1.z*xa[bq].z + wa1.w*xa[bq].w
                                    + wb1.x*xb[bq].x + wb1.y*xb[bq].y + wb1.z*xb[bq].z + wb1.w*xb[bq].w;
                    acc[bq][r0] += hv0;
                    acc[bq][r1] += hv1;
                    (&hq[bq].x)[rp] = pkh(hv0, hv1);
                }
            }
#pragma unroll
            for (int bq = 0; bq < 2; bq++) {
                const int b = bg * 16 + bl0 + bq;
                hatg[(size_t)(b * N_ + n0 + nl) * 64 + le] = hq[bq];
            }
        }

        __syncthreads();                 // all waves done reading wlds
        if (cc < 2) {
#pragma unroll
            for (int i = 0; i < 4; i++) {   // vmcnt wait auto-inserted here
                const int wc = g_f[i] >> 1;
                *(float4*)(wlds + (g_nl[i] * 64 + g_f[i]) * 64 + (g_q ^ (wc & 7)) * 4) = wreg[i];
            }
            __syncthreads();             // wlds ready for next chunk
        }
    }

    // epilogue: t=0 partials (x 1/32), fp16, [slab][b 16][256 half2]
    __half2* pout = p1 + (size_t)(bg * HSLOT + slot) * (16 * 256);
#pragma unroll
    for (int bq = 0; bq < 2; bq++) {
        uint4 st;
        st.x = pkh(acc[bq][0]*0.03125f, acc[bq][1]*0.03125f);
        st.y = pkh(acc[bq][2]*0.03125f, acc[bq][3]*0.03125f);
        st.z = pkh(acc[bq][4]*0.03125f, acc[bq][5]*0.03125f);
        st.w = pkh(acc[bq][6]*0.03125f, acc[bq][7]*0.03125f);
        *(uint4*)(pout + (bl0 + bq) * 256 + le * 4) = st;
    }
}

// ---------------- caps_route: one routing pass over materialized fp16 hat --
// Verified R10/R3 structure: unit u = 48 n = exactly the slot band one XCD
// wrote (u%8 == writing xcd); block mapping u = 8*ug + (bid&7) puts the
// reader on that XCD -> same-L2 hat reads. v[6] + 6-chain batched softmax.
// R15 fix: (512,4)->(512,2) -- R3 ran this in the 64-VGPR spill regime.
__global__ __launch_bounds__(STH, 2) void caps_route(
    const uint4* __restrict__ hatg, const float* __restrict__ accb,
    float* __restrict__ p2)
{
    __shared__ float red[8 * 512];
    const int xcd  = blockIdx.x & 7;
    const int rest = blockIdx.x >> 3;        // 0..191
    const int ug   = rest % 3;
    const int b    = rest / 3;               // 0..63
    const int u    = 8 * ug + xcd;           // 0..23, u%8 == xcd
    const int tid  = threadIdx.x;
    const int w    = tid >> 6;
    const int lane = tid & 63;
    const int c    = lane & 31;
    const int h    = lane >> 5;
    const int le   = 2 * c + h;

    const float* ap = accb + (size_t)b * 512 + le * 8;
    const float4 a0 = *(const float4*)ap;
    const float4 a1 = *(const float4*)(ap + 4);

    const uint4* hb = hatg + (size_t)(b * N_ + u * 48) * 64 + le;

    uint4 v[6];
#pragma unroll
    for (int m = 0; m < 6; m++)
        v[m] = hb[(size_t)(w + 8 * m) * 64];

    float lg[6], sm[6];
#pragma unroll
    for (int m = 0; m < 6; m++) {
        const float2 f0 = uph(v[m].x);
        const float2 f1 = uph(v[m].y);
        const float2 f2 = uph(v[m].z);
        const float2 f3 = uph(v[m].w);
        lg[m] = f0.x*a0.x + f0.y*a0.y + f1.x*a0.z + f1.y*a0.w
              + f2.x*a1.x + f2.y*a1.y + f3.x*a1.z + f3.y*a1.w;
    }
#pragma unroll
    for (int m = 0; m < 6; m++) lg[m] += __shfl_xor(lg[m], 32, 64);  // combine i-halves
#pragma unroll
    for (int m = 0; m < 6; m++) { lg[m] = __expf(lg[m]); sm[m] = lg[m]; }
#pragma unroll
    for (int d = 16; d >= 1; d >>= 1)
#pragma unroll
        for (int m = 0; m < 6; m++) sm[m] += __shfl_xor(sm[m], d, 64);  // sum over c

    float acc[8] = {0.f,0.f,0.f,0.f,0.f,0.f,0.f,0.f};
#pragma unroll
    for (int m = 0; m < 6; m++) {
        const float sc = lg[m] * __builtin_amdgcn_rcpf(sm[m]);
        const float2 f0 = uph(v[m].x);
        const float2 f1 = uph(v[m].y);
        const float2 f2 = uph(v[m].z);
        const float2 f3 = uph(v[m].w);
        acc[0] += sc * f0.x; acc[1] += sc * f0.y;
        acc[2] += sc * f1.x; acc[3] += sc * f1.y;
        acc[4] += sc * f2.x; acc[5] += sc * f2.y;
        acc[6] += sc * f3.x; acc[7] += sc * f3.y;
    }
    // block reduce over 8 waves
    *(float4*)(red + w * 512 + le * 8)     = make_float4(acc[0], acc[1], acc[2], acc[3]);
    *(float4*)(red + w * 512 + le * 8 + 4) = make_float4(acc[4], acc[5], acc[6], acc[7]);
    __syncthreads();
    float vs = 0.f;
#pragma unroll
    for (int s = 0; s < 8; s++) vs += red[s * 512 + tid];
    p2[(size_t)(b * NOCT + u) * 512 + tid] = vs;
}

// ---------------- caps_r1: reduce 768 fp16 slot-slabs (t=0), squash --------
// p1 layout [bg(4)*HSLOT + slot][16 b][256 half2]; verified R6 structure.
__global__ __launch_bounds__(512) void caps_r1(
    const __half2* __restrict__ p1, float* __restrict__ accb,
    float* __restrict__ out, int t)
{
    const int b   = blockIdx.x >> 2;     // 0..63
    const int q   = blockIdx.x & 3;
    const int tid = threadIdx.x;
    const int ep  = tid >> 3;            // 0..63: e-pair within q-range
    const int p   = tid & 7;             // 8-way slab split
    const int bg  = b >> 4, bl = b & 15;
    const __half2* base = p1 + (size_t)bg * HSLOT * 4096 + bl * 256 + (q * 64 + ep);
    float vx = 0.f, vy = 0.f;
#pragma unroll 8
    for (int ch = p; ch < HSLOT; ch += 8) {
        const float2 f = __half22float2(base[(size_t)ch * 4096]);
        vx += f.x; vy += f.y;
    }
    vx += __shfl_xor(vx, 1, 64);  vy += __shfl_xor(vy, 1, 64);
    vx += __shfl_xor(vx, 2, 64);  vy += __shfl_xor(vy, 2, 64);
    vx += __shfl_xor(vx, 4, 64);  vy += __shfl_xor(vy, 4, 64);
    float sq = vx * vx + vy * vy;
    sq += __shfl_xor(sq, 8, 64);
    sq += __shfl_xor(sq, 16, 64);
    sq += __shfl_xor(sq, 32, 64);
    const float scale = sq / (1.f + sq) * rsqrtf(sq + 1e-7f);
    if (p == 0) {
        const int oidx = b * 512 + q * 128 + ep * 2;
        const float ox = vx * scale, oy = vy * scale;
        if (t == 2) { out[oidx] = ox; out[oidx + 1] = oy; }
        else if (t == 0) { accb[oidx] = ox; accb[oidx + 1] = oy; }
        else { accb[oidx] += ox; accb[oidx + 1] += oy; }
    }
}

// ---------------- caps_r2: reduce caps_route's 24 unit-slabs per b ---------
__global__ __launch_bounds__(512) void caps_r2(
    const float* __restrict__ p2, float* __restrict__ accb,
    float* __restrict__ out, int t)
{
    const int b = blockIdx.x;
    const int e = threadIdx.x;               // [c=e>>4][i=e&15]
    const float* base = p2 + (size_t)b * (NOCT * 512) + e;
    float v = 0.f;
#pragma unroll
    for (int s = 0; s < NOCT; s++) v += base[s * 512];
    float sq = v * v;
#pragma unroll
    for (int m = 1; m <= 8; m <<= 1) sq += __shfl_xor(sq, m, 64);  // sum over i
    const float scale = sq / (1.f + sq) * rsqrtf(sq + 1e-7f);
    const float ov = v * scale;
    const int oidx = b * 512 + e;
    if (t == 2) out[oidx] = ov;
    else        accb[oidx] += ov;
}

// ---------------- fallback (R5 path, 16.9 MB ws) ---------------------------
__global__ __launch_bounds__(STH, 2) void caps_s_fb(
    const float* __restrict__ X, const float* __restrict__ W,
    const float* __restrict__ aout, float* __restrict__ partials, int t)
{
    __shared__ float wlds[FCH * 64 * 64];
    __shared__ float xlds[FCH * 16 * 8];
    const int bg = blockIdx.x & 3, slot = blockIdx.x >> 2;
    const int tid = threadIdx.x, w = tid >> 6, lane = tid & 63;
    const int c = lane & 31, h = lane >> 5, bl0 = w * 2, sw = c & 7;
    float areg[2][8] = {};
    if (t > 0) {
#pragma unroll
        for (int bq = 0; bq < 2; bq++) {
            const float* ap = aout + (size_t)(bg * 16 + bl0 + bq) * 512 + c * 16 + h * 8;
            const float4 a0 = *(const float4*)ap; const float4 a1 = *(const float4*)(ap + 4);
            areg[bq][0]=a0.x; areg[bq][1]=a0.y; areg[bq][2]=a0.z; areg[bq][3]=a0.w;
            areg[bq][4]=a1.x; areg[bq][5]=a1.y; areg[bq][6]=a1.z; areg[bq][7]=a1.w;
        }
    }
    float acc[2][8];
#pragma unroll
    for (int bq = 0; bq < 2; bq++)
#pragma unroll
        for (int r = 0; r < 8; r++) acc[bq][r] = 0.f;
    for (int cc = 0; cc < 3; cc++) {
        if (cc) __syncthreads();
        const int n0 = (slot + cc * FSLOT) * FCH;
        for (int G = tid; G < FCH * 1024; G += STH) {
            const int nl = G >> 10, f = (G >> 4) & 63, q = G & 15;
            const int wc = f >> 1, wh = f & 1;
            const float4 v = *(const float4*)(W + (size_t)(wc * N_ + n0 + nl) * 128 + wh * 64 + q * 4);
            *(float4*)(wlds + (nl * 64 + f) * 64 + (q ^ (wc & 7)) * 4) = v;
        }
        if (tid < FCH * 32) {
            const int nl = tid >> 5, bl = (tid >> 1) & 15, qx = tid & 1;
            const float4 v = *(const float4*)(X + (size_t)((bg * 16 + bl) * N_ + n0 + nl) * DI_ + qx * 4);
            *(float4*)(xlds + (nl * 16 + bl) * 8 + qx * 4) = v;
        }
        __syncthreads();
#pragma unroll
        for (int nl = 0; nl < FCH; nl++) {
            float4 xa[2], xb[2];
#pragma unroll
            for (int bq = 0; bq < 2; bq++) {
                const float* xp = xlds + (nl * 16 + bl0 + bq) * 8;
                xa[bq] = *(const float4*)xp; xb[bq] = *(const float4*)(xp + 4);
            }
            float hat[2][8];
            const float* frag = wlds + (nl * 64 + 2 * c + h) * 64;
#pragma unroll
            for (int r = 0; r < 8; r++) {
                const int pa = ((2 * r) ^ sw) * 4; const int pb = pa ^ 4;
                const float4 wa = *(const float4*)(frag + pa);
                const float4 wb = *(const float4*)(frag + pb);
#pragma unroll
                for (int bq = 0; bq < 2; bq++)
                    hat[bq][r] = wa.x*xa[bq].x + wa.y*xa[bq].y + wa.z*xa[bq].z + wa.w*xa[bq].w
                               + wb.x*xb[bq].x + wb.y*xb[bq].y + wb.z*xb[bq].z + wb.w*xb[bq].w;
            }
#pragma unroll
            for (int bq = 0; bq < 2; bq++) {
                float softc;
                if (t > 0) {
                    float lg = hat[bq][0]*areg[bq][0] + hat[bq][1]*areg[bq][1]
                             + hat[bq][2]*areg[bq][2] + hat[bq][3]*areg[bq][3]
                             + hat[bq][4]*areg[bq][4] + hat[bq][5]*areg[bq][5]
                             + hat[bq][6]*areg[bq][6] + hat[bq][7]*areg[bq][7];
                    lg += __shfl_xor(lg, 32, 64);
                    const float e = __expf(lg);
                    float s = e;
#pragma unroll
                    for (int m = 16; m >= 1; m >>= 1) s += __shfl_xor(s, m, 64);
                    softc = e / s;
                } else softc = 1.0f / 32.0f;
#pragma unroll
                for (int r = 0; r < 8; r++) acc[bq][r] += softc * hat[bq][r];
            }
        }
    }
    float* pout = partials + (size_t)(bg * FSLOT + slot) * (16 * 512);
#pragma unroll
    for (int bq = 0; bq < 2; bq++) {
        float* pb = pout + (bl0 + bq) * 512 + c * 16 + h * 8;
        *(float4*)pb       = make_float4(acc[bq][0], acc[bq][1], acc[bq][2], acc[bq][3]);
        *(float4*)(pb + 4) = make_float4(acc[bq][4], acc[bq][5], acc[bq][6], acc[bq][7]);
    }
}

__global__ __launch_bounds__(256) void caps_r1_fb(
    const float* __restrict__ partials, float* __restrict__ accb,
    float* __restrict__ out, int t)
{
    const int b   = blockIdx.x >> 2;
    const int q   = blockIdx.x & 3;
    const int tid = threadIdx.x;
    const int e   = q * 128 + (tid >> 1);
    const int p   = tid & 1;
    const int bg  = b >> 4, bl = b & 15;
    const float* base = partials + (size_t)bg * FSLOT * 8192 + (size_t)bl * 512 + e;
    float v = 0.f;
#pragma unroll 8
    for (int ch = p; ch < FSLOT; ch += 2)
        v += base[(size_t)ch * 8192];
    v += __shfl_xor(v, 1, 64);
    float sq = v * v;
#pragma unroll
    for (int m = 2; m <= 16; m <<= 1) sq += __shfl_xor(sq, m, 64);
    const float scale = sq / (1.f + sq) * rsqrtf(sq + 1e-7f);
    const float ov = v * scale;
    if (p == 0) {
        const int oidx = b * 512 + e;
        if (t == 2) out[oidx] = ov;
        else        accb[oidx] = (t == 0) ? ov : (accb[oidx] + ov);
    }
}

extern "C" void kernel_launch(void* const* d_in, const int* in_sizes, int n_in,
                              void* d_out, int out_size, void* d_ws, size_t ws_size,
                              hipStream_t stream) {
    const float* X = (const float*)d_in[0];   // [B,N,DI]
    const float* W = (const float*)d_in[1];   // [C,N,DC,DI]
    float* out = (float*)d_out;               // [B,C,DC]

    const size_t hat_b = (size_t)B_ * N_ * 512 * 2;        // 75,497,472 (fp16)
    const size_t p1_b  = (size_t)4 * HSLOT * 4096 * 4;     // 12,582,912 (fp16)
    const size_t p2_b  = (size_t)B_ * NOCT * 512 * 4;      //  3,145,728
    const size_t acc_b = (size_t)B_ * 512 * 4;             //    131,072

    if (ws_size >= hat_b + p1_b + p2_b + acc_b) {
        char* ws = (char*)d_ws;
        uint4*   hatg = (uint4*)ws;
        __half2* p1   = (__half2*)(ws + hat_b);
        float*   p2   = (float*)(ws + hat_b + p1_b);
        float*   accb = (float*)(ws + hat_b + p1_b + p2_b);
        caps_hat  <<<768, STH, 0, stream>>>(X, W, hatg, p1);
        caps_r1   <<<256, 512, 0, stream>>>(p1, accb, out, 0);
        caps_route<<<B_ * NOCT, STH, 0, stream>>>(hatg, accb, p2);
        caps_r2   <<<64, 512, 0, stream>>>(p2, accb, out, 1);
        caps_route<<<B_ * NOCT, STH, 0, stream>>>(hatg, accb, p2);
        caps_r2   <<<64, 512, 0, stream>>>(p2, accb, out, 2);
    } else {
        float* partials = (float*)d_ws;
        float* accb = partials + (size_t)512 * 8192;
        for (int t = 0; t < 3; t++) {
            caps_s_fb<<<512, STH, 0, stream>>>(X, W, accb, partials, t);
            caps_r1_fb<<<256, 256, 0, stream>>>(partials, accb, out, t);
        }
    }
}

// Round 9
// 129.680 us; speedup vs baseline: 1.6180x; 1.1112x over previous
//
#include <hip/hip_runtime.h>
#include <hip/hip_bf16.h>
#include <hip/hip_fp16.h>

#define B_  64
#define C_  32
#define N_  1152
#define DI_ 8
#define DC_ 16
#define STH 512              // 8 waves

// main-path geometry
#define HCH 2                // n's per staged chunk (wlds 32KB)
#define HSLOT 192            // chunk-slots; slot handles chunks slot, +192, +384
#define NOCT 24              // route units of 48 n = one XCD's slot band

// fallback geometry (R5 path)
#define FCH 3
#define FSLOT 128

static __device__ __forceinline__ unsigned pkh(float a, float b) {
    __half2 t = __float22half2_rn(make_float2(a, b));
    return *reinterpret_cast<unsigned*>(&t);
}
static __device__ __forceinline__ float2 uph(unsigned u) {
    __half2 h; *reinterpret_cast<unsigned*>(&h) = u;
    return __half22float2(h);
}

// ---------------- caps_hat: hat = W@x once, fp16 out, + t=0 partials -------
// R16: the allocator targets 8 waves/EU (64 VGPR) whenever LDS=32KB, and it
// SPILLS to get there -- launch bounds don't override it (R8: VGPR=60,
// WRITE 142MB vs 88 expected). So fit 64 for real: bq=1 (wave owns ONE b;
// 8 b/block, grid 1536 = 8bg x 192 slots), no reg-prefetch (latency hidden
// by 4 resident blocks/CU = 32 waves/CU). Peak live ~46 VGPR.
// XCD banding: bid&7 = xcd owns slots [24*xcd, 24*xcd+24) -- all 8 bg-blocks
// of a slot share one XCD so W is fetched once per L2; route units align.
__global__ __launch_bounds__(STH, 2) void caps_hat(
    const float* __restrict__ X, const float* __restrict__ W,
    uint4* __restrict__ hatg, __half2* __restrict__ p1)
{
    __shared__ float wlds[HCH * 64 * 64];    // [nl][f=2c+h][phys quad q^(c&7)]

    const int xcd  = blockIdx.x & 7;
    const int k    = blockIdx.x >> 3;        // 0..191
    const int bg   = k & 7;                  // 0..7 (8 b's each)
    const int slot = 24 * xcd + (k >> 3);    // 0..191, contiguous band per XCD

    const int tid  = threadIdx.x;
    const int lane = tid & 63;
    const int c    = lane & 31;
    const int h    = lane >> 5;
    const int le   = 2 * c + h;
    const int sw   = c & 7;
    const int wu   = __builtin_amdgcn_readfirstlane(tid) >> 6;  // uniform wave id
    const int b    = bg * 8 + wu;            // this wave's batch index

    float acc[8];
#pragma unroll
    for (int r = 0; r < 8; r++) acc[r] = 0.f;

    for (int cc = 0; cc < 3; cc++) {
        if (cc) __syncthreads();
        const int n0 = (slot + cc * HSLOT) * HCH;

#pragma unroll
        for (int G = tid; G < HCH * 1024; G += STH) {   // 4 iters
            const int nl = G >> 10, f = (G >> 4) & 63, q = G & 15;
            const int wc = f >> 1, wh = f & 1;
            const float4 v = *(const float4*)(W + (size_t)(wc * N_ + n0 + nl) * 128 + wh * 64 + q * 4);
            *(float4*)(wlds + (nl * 64 + f) * 64 + (q ^ (wc & 7)) * 4) = v;
        }
        __syncthreads();

#pragma unroll
        for (int nl = 0; nl < HCH; nl++) {
            const float* xp = X + ((size_t)b * N_ + n0 + nl) * DI_;
            const float4 xa = *(const float4*)xp;
            const float4 xb = *(const float4*)(xp + 4);
            uint4 hq;
            const float* frag = wlds + (nl * 64 + le) * 64;
#pragma unroll
            for (int rp = 0; rp < 4; rp++) {
                const int r0 = 2 * rp, r1 = r0 + 1;
                const int pa0 = ((2 * r0) ^ sw) * 4;
                const int pb0 = pa0 ^ 4;
                const int pa1 = ((2 * r1) ^ sw) * 4;
                const int pb1 = pa1 ^ 4;
                const float4 wa0 = *(const float4*)(frag + pa0);
                const float4 wb0 = *(const float4*)(frag + pb0);
                const float4 wa1 = *(const float4*)(frag + pa1);
                const float4 wb1 = *(const float4*)(frag + pb1);
                const float hv0 = wa0.x*xa.x + wa0.y*xa.y + wa0.z*xa.z + wa0.w*xa.w
                                + wb0.x*xb.x + wb0.y*xb.y + wb0.z*xb.z + wb0.w*xb.w;
                const float hv1 = wa1.x*xa.x + wa1.y*xa.y + wa1.z*xa.z + wa1.w*xa.w
                                + wb1.x*xb.x + wb1.y*xb.y + wb1.z*xb.z + wb1.w*xb.w;
                acc[r0] += hv0;
                acc[r1] += hv1;
                (&hq.x)[rp] = pkh(hv0, hv1);
            }
            hatg[(size_t)(b * N_ + n0 + nl) * 64 + le] = hq;
        }
    }

    // epilogue: t=0 partials (x 1/32), fp16, slab = [8 b][256 half2]
    __half2* pout = p1 + (size_t)(bg * HSLOT + slot) * (8 * 256);
    uint4 st;
    st.x = pkh(acc[0]*0.03125f, acc[1]*0.03125f);
    st.y = pkh(acc[2]*0.03125f, acc[3]*0.03125f);
    st.z = pkh(acc[4]*0.03125f, acc[5]*0.03125f);
    st.w = pkh(acc[6]*0.03125f, acc[7]*0.03125f);
    *(uint4*)(pout + wu * 256 + le * 4) = st;
}

// ---------------- caps_route: one routing pass over materialized fp16 hat --
// Verified R10 structure (unit u = the 48-n band one XCD wrote; u%8 == bid&7
// -> same-L2 hat reads). R16: softmax chains batched 3-at-a-time (was 6) to
// fit the 64-VGPR regime; v[6] still loaded up front for memory-level par.
__global__ __launch_bounds__(STH, 2) void caps_route(
    const uint4* __restrict__ hatg, const float* __restrict__ accb,
    float* __restrict__ p2)
{
    __shared__ float red[8 * 512];
    const int xcd  = blockIdx.x & 7;
    const int rest = blockIdx.x >> 3;        // 0..191
    const int ug   = rest % 3;
    const int b    = rest / 3;               // 0..63
    const int u    = 8 * ug + xcd;           // 0..23, u%8 == xcd
    const int tid  = threadIdx.x;
    const int w    = tid >> 6;
    const int lane = tid & 63;
    const int c    = lane & 31;
    const int h    = lane >> 5;
    const int le   = 2 * c + h;

    const float* ap = accb + (size_t)b * 512 + le * 8;
    const float4 a0 = *(const float4*)ap;
    const float4 a1 = *(const float4*)(ap + 4);

    const uint4* hb = hatg + (size_t)(b * N_ + u * 48) * 64 + le;

    uint4 v[6];
#pragma unroll
    for (int m = 0; m < 6; m++)
        v[m] = hb[(size_t)(w + 8 * m) * 64];

    float acc[8] = {0.f,0.f,0.f,0.f,0.f,0.f,0.f,0.f};
#pragma unroll
    for (int g = 0; g < 2; g++) {
        float lg[3], sm[3];
#pragma unroll
        for (int j = 0; j < 3; j++) {
            const uint4 vv = v[g * 3 + j];
            const float2 f0 = uph(vv.x);
            const float2 f1 = uph(vv.y);
            const float2 f2 = uph(vv.z);
            const float2 f3 = uph(vv.w);
            lg[j] = f0.x*a0.x + f0.y*a0.y + f1.x*a0.z + f1.y*a0.w
                  + f2.x*a1.x + f2.y*a1.y + f3.x*a1.z + f3.y*a1.w;
        }
#pragma unroll
        for (int j = 0; j < 3; j++) lg[j] += __shfl_xor(lg[j], 32, 64);  // i-halves
#pragma unroll
        for (int j = 0; j < 3; j++) { lg[j] = __expf(lg[j]); sm[j] = lg[j]; }
#pragma unroll
        for (int d = 16; d >= 1; d >>= 1)
#pragma unroll
            for (int j = 0; j < 3; j++) sm[j] += __shfl_xor(sm[j], d, 64);  // over c
#pragma unroll
        for (int j = 0; j < 3; j++) {
            const float sc = lg[j] * __builtin_amdgcn_rcpf(sm[j]);
            const uint4 vv = v[g * 3 + j];
            const float2 f0 = uph(vv.x);
            const float2 f1 = uph(vv.y);
            const float2 f2 = uph(vv.z);
            const float2 f3 = uph(vv.w);
            acc[0] += sc * f0.x; acc[1] += sc * f0.y;
            acc[2] += sc * f1.x; acc[3] += sc * f1.y;
            acc[4] += sc * f2.x; acc[5] += sc * f2.y;
            acc[6] += sc * f3.x; acc[7] += sc * f3.y;
        }
    }
    // block reduce over 8 waves
    *(float4*)(red + w * 512 + le * 8)     = make_float4(acc[0], acc[1], acc[2], acc[3]);
    *(float4*)(red + w * 512 + le * 8 + 4) = make_float4(acc[4], acc[5], acc[6], acc[7]);
    __syncthreads();
    float vs = 0.f;
#pragma unroll
    for (int s = 0; s < 8; s++) vs += red[s * 512 + tid];
    p2[(size_t)(b * NOCT + u) * 512 + tid] = vs;
}

// ---------------- caps_r1: reduce 1536 fp16 slot-slabs (t=0), squash -------
// p1 layout [bg(8)*HSLOT + slot][8 b][256 half2]
__global__ __launch_bounds__(512) void caps_r1(
    const __half2* __restrict__ p1, float* __restrict__ accb,
    float* __restrict__ out, int t)
{
    const int b   = blockIdx.x >> 2;     // 0..63
    const int q   = blockIdx.x & 3;
    const int tid = threadIdx.x;
    const int ep  = tid >> 3;            // 0..63: e-pair within q-range
    const int p   = tid & 7;             // 8-way slab split
    const int bg  = b >> 3, bl = b & 7;
    const __half2* base = p1 + (size_t)bg * HSLOT * 2048 + bl * 256 + (q * 64 + ep);
    float vx = 0.f, vy = 0.f;
#pragma unroll 8
    for (int ch = p; ch < HSLOT; ch += 8) {
        const float2 f = __half22float2(base[(size_t)ch * 2048]);
        vx += f.x; vy += f.y;
    }
    vx += __shfl_xor(vx, 1, 64);  vy += __shfl_xor(vy, 1, 64);
    vx += __shfl_xor(vx, 2, 64);  vy += __shfl_xor(vy, 2, 64);
    vx += __shfl_xor(vx, 4, 64);  vy += __shfl_xor(vy, 4, 64);
    float sq = vx * vx + vy * vy;
    sq += __shfl_xor(sq, 8, 64);
    sq += __shfl_xor(sq, 16, 64);
    sq += __shfl_xor(sq, 32, 64);
    const float scale = sq / (1.f + sq) * rsqrtf(sq + 1e-7f);
    if (p == 0) {
        const int oidx = b * 512 + q * 128 + ep * 2;
        const float ox = vx * scale, oy = vy * scale;
        if (t == 2) { out[oidx] = ox; out[oidx + 1] = oy; }
        else if (t == 0) { accb[oidx] = ox; accb[oidx + 1] = oy; }
        else { accb[oidx] += ox; accb[oidx + 1] += oy; }
    }
}

// ---------------- caps_r2: reduce caps_route's 24 unit-slabs per b ---------
__global__ __launch_bounds__(512) void caps_r2(
    const float* __restrict__ p2, float* __restrict__ accb,
    float* __restrict__ out, int t)
{
    const int b = blockIdx.x;
    const int e = threadIdx.x;               // [c=e>>4][i=e&15]
    const float* base = p2 + (size_t)b * (NOCT * 512) + e;
    float v = 0.f;
#pragma unroll
    for (int s = 0; s < NOCT; s++) v += base[s * 512];
    float sq = v * v;
#pragma unroll
    for (int m = 1; m <= 8; m <<= 1) sq += __shfl_xor(sq, m, 64);  // sum over i
    const float scale = sq / (1.f + sq) * rsqrtf(sq + 1e-7f);
    const float ov = v * scale;
    const int oidx = b * 512 + e;
    if (t == 2) out[oidx] = ov;
    else        accb[oidx] += ov;
}

// ---------------- fallback (R5 path, 16.9 MB ws) ---------------------------
__global__ __launch_bounds__(STH, 2) void caps_s_fb(
    const float* __restrict__ X, const float* __restrict__ W,
    const float* __restrict__ aout, float* __restrict__ partials, int t)
{
    __shared__ float wlds[FCH * 64 * 64];
    __shared__ float xlds[FCH * 16 * 8];
    const int bg = blockIdx.x & 3, slot = blockIdx.x >> 2;
    const int tid = threadIdx.x, w = tid >> 6, lane = tid & 63;
    const int c = lane & 31, h = lane >> 5, bl0 = w * 2, sw = c & 7;
    float areg[2][8] = {};
    if (t > 0) {
#pragma unroll
        for (int bq = 0; bq < 2; bq++) {
            const float* ap = aout + (size_t)(bg * 16 + bl0 + bq) * 512 + c * 16 + h * 8;
            const float4 a0 = *(const float4*)ap; const float4 a1 = *(const float4*)(ap + 4);
            areg[bq][0]=a0.x; areg[bq][1]=a0.y; areg[bq][2]=a0.z; areg[bq][3]=a0.w;
            areg[bq][4]=a1.x; areg[bq][5]=a1.y; areg[bq][6]=a1.z; areg[bq][7]=a1.w;
        }
    }
    float acc[2][8];
#pragma unroll
    for (int bq = 0; bq < 2; bq++)
#pragma unroll
        for (int r = 0; r < 8; r++) acc[bq][r] = 0.f;
    for (int cc = 0; cc < 3; cc++) {
        if (cc) __syncthreads();
        const int n0 = (slot + cc * FSLOT) * FCH;
        for (int G = tid; G < FCH * 1024; G += STH) {
            const int nl = G >> 10, f = (G >> 4) & 63, q = G & 15;
            const int wc = f >> 1, wh = f & 1;
            const float4 v = *(const float4*)(W + (size_t)(wc * N_ + n0 + nl) * 128 + wh * 64 + q * 4);
            *(float4*)(wlds + (nl * 64 + f) * 64 + (q ^ (wc & 7)) * 4) = v;
        }
        if (tid < FCH * 32) {
            const int nl = tid >> 5, bl = (tid >> 1) & 15, qx = tid & 1;
            const float4 v = *(const float4*)(X + (size_t)((bg * 16 + bl) * N_ + n0 + nl) * DI_ + qx * 4);
            *(float4*)(xlds + (nl * 16 + bl) * 8 + qx * 4) = v;
        }
        __syncthreads();
#pragma unroll
        for (int nl = 0; nl < FCH; nl++) {
            float4 xa[2], xb[2];
#pragma unroll
            for (int bq = 0; bq < 2; bq++) {
                const float* xp = xlds + (nl * 16 + bl0 + bq) * 8;
                xa[bq] = *(const float4*)xp; xb[bq] = *(const float4*)(xp + 4);
            }
            float hat[2][8];
            const float* frag = wlds + (nl * 64 + 2 * c + h) * 64;
#pragma unroll
            for (int r = 0; r < 8; r++) {
                const int pa = ((2 * r) ^ sw) * 4; const int pb = pa ^ 4;
                const float4 wa = *(const float4*)(frag + pa);
                const float4 wb = *(const float4*)(frag + pb);
#pragma unroll
                for (int bq = 0; bq < 2; bq++)
                    hat[bq][r] = wa.x*xa[bq].x + wa.y*xa[bq].y + wa.z*xa[bq].z + wa.w*xa[bq].w
                               + wb.x*xb[bq].x + wb.y*xb[bq].y + wb.z*xb[bq].z + wb.w*xb[bq].w;
            }
#pragma unroll
            for (int bq = 0; bq < 2; bq++) {
                float softc;
                if (t > 0) {
                    float lg = hat[bq][0]*areg[bq][0] + hat[bq][1]*areg[bq][1]
                             + hat[bq][2]*areg[bq][2] + hat[bq][3]*areg[bq][3]
                             + hat[bq][4]*areg[bq][4] + hat[bq][5]*areg[bq][5]
                             + hat[bq][6]*areg[bq][6] + hat[bq][7]*areg[bq][7];
                    lg += __shfl_xor(lg, 32, 64);
                    const float e = __expf(lg);
                    float s = e;
#pragma unroll
                    for (int m = 16; m >= 1; m >>= 1) s += __shfl_xor(s, m, 64);
                    softc = e / s;
                } else softc = 1.0f / 32.0f;
#pragma unroll
                for (int r = 0; r < 8; r++) acc[bq][r] += softc * hat[bq][r];
            }
        }
    }
    float* pout = partials + (size_t)(bg * FSLOT + slot) * (16 * 512);
#pragma unroll
    for (int bq = 0; bq < 2; bq++) {
        float* pb = pout + (bl0 + bq) * 512 + c * 16 + h * 8;
        *(float4*)pb       = make_float4(acc[bq][0], acc[bq][1], acc[bq][2], acc[bq][3]);
        *(float4*)(pb + 4) = make_float4(acc[bq][4], acc[bq][5], acc[bq][6], acc[bq][7]);
    }
}

__global__ __launch_bounds__(256) void caps_r1_fb(
    const float* __restrict__ partials, float* __restrict__ accb,
    float* __restrict__ out, int t)
{
    const int b   = blockIdx.x >> 2;
    const int q   = blockIdx.x & 3;
    const int tid = threadIdx.x;
    const int e   = q * 128 + (tid >> 1);
    const int p   = tid & 1;
    const int bg  = b >> 4, bl = b & 15;
    const float* base = partials + (size_t)bg * FSLOT * 8192 + (size_t)bl * 512 + e;
    float v = 0.f;
#pragma unroll 8
    for (int ch = p; ch < FSLOT; ch += 2)
        v += base[(size_t)ch * 8192];
    v += __shfl_xor(v, 1, 64);
    float sq = v * v;
#pragma unroll
    for (int m = 2; m <= 16; m <<= 1) sq += __shfl_xor(sq, m, 64);
    const float scale = sq / (1.f + sq) * rsqrtf(sq + 1e-7f);
    const float ov = v * scale;
    if (p == 0) {
        const int oidx = b * 512 + e;
        if (t == 2) out[oidx] = ov;
        else        accb[oidx] = (t == 0) ? ov : (accb[oidx] + ov);
    }
}

extern "C" void kernel_launch(void* const* d_in, const int* in_sizes, int n_in,
                              void* d_out, int out_size, void* d_ws, size_t ws_size,
                              hipStream_t stream) {
    const float* X = (const float*)d_in[0];   // [B,N,DI]
    const float* W = (const float*)d_in[1];   // [C,N,DC,DI]
    float* out = (float*)d_out;               // [B,C,DC]

    const size_t hat_b = (size_t)B_ * N_ * 512 * 2;        // 75,497,472 (fp16)
    const size_t p1_b  = (size_t)8 * HSLOT * 2048 * 4;     // 12,582,912 (fp16)
    const size_t p2_b  = (size_t)B_ * NOCT * 512 * 4;      //  3,145,728
    const size_t acc_b = (size_t)B_ * 512 * 4;             //    131,072

    if (ws_size >= hat_b + p1_b + p2_b + acc_b) {
        char* ws = (char*)d_ws;
        uint4*   hatg = (uint4*)ws;
        __half2* p1   = (__half2*)(ws + hat_b);
        float*   p2   = (float*)(ws + hat_b + p1_b);
        float*   accb = (float*)(ws + hat_b + p1_b + p2_b);
        caps_hat  <<<1536, STH, 0, stream>>>(X, W, hatg, p1);
        caps_r1   <<<256, 512, 0, stream>>>(p1, accb, out, 0);
        caps_route<<<B_ * NOCT, STH, 0, stream>>>(hatg, accb, p2);
        caps_r2   <<<64, 512, 0, stream>>>(p2, accb, out, 1);
        caps_route<<<B_ * NOCT, STH, 0, stream>>>(hatg, accb, p2);
        caps_r2   <<<64, 512, 0, stream>>>(p2, accb, out, 2);
    } else {
        float* partials = (float*)d_ws;
        float* accb = partials + (size_t)512 * 8192;
        for (int t = 0; t < 3; t++) {
            caps_s_fb<<<512, STH, 0, stream>>>(X, W, accb, partials, t);
            caps_r1_fb<<<256, 256, 0, stream>>>(partials, accb, out, t);
        }
    }
}